// Round 8
// baseline (206.739 us; speedup 1.0000x reference)
//
#include <hip/hip_runtime.h>
#include <math.h>

// QuaternionAttention B=4, L=S=2048, H=8, E=64, M=4 (fp32 in/out).
// Round 16: zero-shuffle in-register P, on the round-15 base (129.7us:
// QBLK=256/NTH=512, dbuf krot/vts, swapped-QK lane-local softmax, defer-max).
//
// Key change: QK's key->lane mapping is chosen via the A-operand row address
// so P lands in the PV A-fragment layout directly. Lane nn loads
// krot[ks2*32 + (nn>>2)*8 + hf*4 + (nn&3)]  (sigma permutation); then lane
// (quad,nn) holds keys ks2*32+quad*8+{hf*4+r} for Q-row nn == exactly the
// pf fragment PV needs. Removes: pss (16KB), 8 ds_write_b64 + 4 ds_read_b128
// per wave-tile (~23% of LDS instrs), and the softmax->PV LDS dependency.
// Also: V^T swizzle upgraded to s(row)=(row&7)^(row>>3) on both sides --
// old (row&7)-only swizzle left V^T writes 4-way bank-conflicted (rows
// stride 4 -> only 2 distinct groups per 8-lane subgroup); new form gives 8
// distinct (verified read side stays a permutation: se = nn^(et*2+(nn>>3))).
// qstage rows padded 64->68 floats (one-time 8-way read conflict).
// Everything else (dbuf schedule, setprio, raw v_sin/v_cos, defer-max,
// epilogue) is the round-15 proven code.

#define B_ 4
#define L_ 2048
#define S_ 2048
#define H_ 8
#define E_ 64
#define M_ 4
#define QBLK 256
#define NTH 512
#define NTILES 32

#define KROT_OFF 0          // 2 x 32KB
#define VTS_OFF  65536      // 2 x 8KB
#define QTRC_OFF 73728      // overlay vts buf1 (dead before BUILD(1))
#define QTRS_OFF 77824
#define SMEM_BYTES 81920

typedef _Float16 f16x4 __attribute__((ext_vector_type(4)));
typedef _Float16 f16x8 __attribute__((ext_vector_type(8)));
typedef __fp16 fp16x2 __attribute__((ext_vector_type(2)));   // cvt_pkrtz return type
typedef float f32x4 __attribute__((ext_vector_type(4)));

union H4U { f16x4 h; fp16x2 p[2]; };
union H8U { f16x8 h; fp16x2 p[4]; };
union F4U { float4 v; float f[4]; };

#if __has_builtin(__builtin_amdgcn_sinf) && __has_builtin(__builtin_amdgcn_cosf)
#define FSINCOS(ang, s, c) do { float _rv = (ang) * 0.15915494309189535f; \
    (s) = __builtin_amdgcn_sinf(_rv); (c) = __builtin_amdgcn_cosf(_rv); } while (0)
#else
#define FSINCOS(ang, s, c) __sincosf((ang), &(s), &(c))
#endif

__device__ __forceinline__ f16x4 cvt4(float x, float y, float z, float w) {
    H4U r;
    r.p[0] = __builtin_amdgcn_cvt_pkrtz(x, y);
    r.p[1] = __builtin_amdgcn_cvt_pkrtz(z, w);
    return r.h;
}
__device__ __forceinline__ f16x8 cvt8(const float* v) {
    H8U r;
#pragma unroll
    for (int i = 0; i < 4; ++i) r.p[i] = __builtin_amdgcn_cvt_pkrtz(v[2 * i], v[2 * i + 1]);
    return r.h;
}

__global__ __launch_bounds__(NTH)
void qattn9(const float* __restrict__ qp, const float* __restrict__ kp,
            const float* __restrict__ vp,
            const float* __restrict__ qo, const float* __restrict__ qt,
            const float* __restrict__ ko, const float* __restrict__ ktt,
            float* __restrict__ out)
{
    // XCD-chunked swizzle (256 blocks, bijective): each XCD gets 32
    // consecutive nl = 4 (b,h) groups.
    const int bid0 = blockIdx.x;                  // 0..255
    const int nl = (bid0 & 7) * 32 + (bid0 >> 3);
    const int l0 = (nl & 7) * QBLK;
    const int h  = (nl >> 3) & 7;
    const int b  = nl >> 6;
    const int t  = threadIdx.x;
    const int wv   = t >> 6;                      // 0..7
    const int lane = t & 63;
    const int quad = lane >> 4;
    const int nn   = lane & 15;

    __shared__ __align__(16) unsigned char smem[SMEM_BYTES];
    float (*qstage)[68] = reinterpret_cast<float (*)[68]>(smem);           // 69.6KB overlay
    float (*qtrc)[4] = reinterpret_cast<float (*)[4]>(smem + QTRC_OFF);
    float (*qtrs)[4] = reinterpret_cast<float (*)[4]>(smem + QTRS_OFF);

    const float* kb0 = kp  + ((size_t)((b * S_) * H_ + h)) * E_;
    const float* vb0 = vp  + ((size_t)((b * S_) * H_ + h)) * E_;
    const float* kob = ko  + ((size_t)((b * S_) * H_ + h)) * M_;
    const float* ktb = ktt + ((size_t)((b * S_) * H_ + h)) * M_;

    // K_rot build roles: 8 threads per key = 4 components x 2 e-halves
    const int key_r = t >> 3;       // 0..63
    const int ccr   = (t >> 1) & 3; // component
    const int eh    = t & 1;        // e-half within component
    const int swz   = key_r & 7;
    // V^T roles (upper 256 threads)
    const int tt = t & 255;
    const int kg = tt >> 4;         // key group (4 keys)
    const int eg = tt & 15;         // e group (4 e's)

    // ---- register pipeline: next tile's K slices, trig, V rows ----
    F4U kA[2], kB[2], omR, thR, vv[4];
    auto LOAD = [&](int s0) {
        const float* kr = kb0 + (size_t)(s0 + key_r) * (H_ * E_);
        kA[0].v = *(const float4*)(kr + ccr * 16 + eh * 8);            // a = k[cc]
        kA[1].v = *(const float4*)(kr + ccr * 16 + eh * 8 + 4);
        kB[0].v = *(const float4*)(kr + (ccr ^ 2) * 16 + eh * 8);      // b = k[cc^2]
        kB[1].v = *(const float4*)(kr + (ccr ^ 2) * 16 + eh * 8 + 4);
        omR.v = *(const float4*)(kob + (size_t)(s0 + key_r) * (H_ * M_));
        thR.v = *(const float4*)(ktb + (size_t)(s0 + key_r) * (H_ * M_));
        if (t >= 256) {
#pragma unroll
            for (int j = 0; j < 4; ++j)
                vv[j].v = *(const float4*)(vb0 + (size_t)(s0 + kg * 4 + j) * (H_ * E_) + eg * 4);
        }
    };

    // ---- build K_rot + V^T into the given LDS buffers from pipeline regs ----
    auto BUILD = [&](int s0, int koff, int voff) {
        _Float16 (*krw)[256] = reinterpret_cast<_Float16 (*)[256]>(smem + koff);
        _Float16 (*vtw)[64]  = reinterpret_cast<_Float16 (*)[64]>(smem + voff);
        {   // K signs: c0:-, c1:-, c2:+, c3:+
            float af[8], bf[8];
#pragma unroll
            for (int i2 = 0; i2 < 4; ++i2) {
                af[i2]     = kA[0].f[i2];
                af[4 + i2] = kA[1].f[i2];
                bf[i2]     = kB[0].f[i2];
                bf[4 + i2] = kB[1].f[i2];
            }
            float posk = (float)(s0 + key_r) * (1.0f / S_);
            float kcv[4], ksv[4];
#pragma unroll
            for (int m = 0; m < 4; ++m) {
                float ang = fmaf(omR.f[m], posk, thR.f[m]);
                FSINCOS(ang, ksv[m], kcv[m]);
            }
            const float sgn = (ccr >= 2) ? 1.f : -1.f;
#pragma unroll
            for (int m = 0; m < 4; ++m) {
                float cm = kcv[m], sm = ksv[m] * sgn;
                float vals[8];
#pragma unroll
                for (int i = 0; i < 8; ++i)
                    vals[i] = fmaf(bf[i], sm, af[i] * cm);
                int ch = (m * 8) | ((ccr * 2 + eh) ^ swz);
                *(f16x8*)&krw[key_r][ch * 8] = cvt8(vals);
            }
        }
        if (t >= 256) {   // V^T 4x4 register-block transpose, s(row) swizzle
#pragma unroll
            for (int e = 0; e < 4; ++e) {
                int row = eg * 4 + e;
                int srow = ((row & 7) ^ (row >> 3)) & 7;
                int ch = (kg >> 1) ^ srow;
                *(f16x4*)&vtw[row][ch * 8 + (kg & 1) * 4] =
                    cvt4(vv[0].f[e], vv[1].f[e], vv[2].f[e], vv[3].f[e]);
            }
        }
    };

    LOAD(0);   // tile-0 loads fly under Q_rot construction

    // ---- build Q_rot A-fragments once per block (scale log2(e)/32 folded) ----
    // Two sets per wave: set s covers rows wv*32 + s*16 + (0..15).
    f16x8 qa[2][8];
    {
        const float* qb = qp + ((size_t)((b * L_ + l0) * H_ + h)) * E_;
#pragma unroll
        for (int i = 0; i < 8; ++i) {
            int idx = t + NTH * i;                 // 0..4095
            int row = idx >> 4, c16 = idx & 15;
            *(float4*)&qstage[row][c16 * 4] =
                *(const float4*)(qb + (size_t)row * (H_ * E_) + c16 * 4);
        }
        {
            int row = t >> 1, m0 = (t & 1) * 2;    // 256 rows x 2 m-pairs
#pragma unroll
            for (int dm = 0; dm < 2; ++dm) {
                int m = m0 + dm;
                size_t off = (size_t)((b * L_ + l0 + row) * H_ + h) * M_ + m;
                float ang = qo[off] * ((float)(l0 + row) * (1.0f / L_)) + qt[off];
                float sv, cv;
                FSINCOS(ang, sv, cv);
                qtrc[row][m] = cv;
                qtrs[row][m] = sv;
            }
        }
        __syncthreads();
#pragma unroll
        for (int set = 0; set < 2; ++set) {
            const int row = wv * 32 + set * 16 + nn;   // A-frag row = lane&15
            const int i0 = (quad & 1) * 8;
            float sl0[8], sl1[8], sl2[8], sl3[8];
            *(float4*)&sl0[0] = *(float4*)&qstage[row][ 0 + i0];
            *(float4*)&sl0[4] = *(float4*)&qstage[row][ 4 + i0];
            *(float4*)&sl1[0] = *(float4*)&qstage[row][16 + i0];
            *(float4*)&sl1[4] = *(float4*)&qstage[row][20 + i0];
            *(float4*)&sl2[0] = *(float4*)&qstage[row][32 + i0];
            *(float4*)&sl2[4] = *(float4*)&qstage[row][36 + i0];
            *(float4*)&sl3[0] = *(float4*)&qstage[row][48 + i0];
            *(float4*)&sl3[4] = *(float4*)&qstage[row][52 + i0];
            // even ks -> c = quad>>1 (0 or 1); odd ks -> c+2.
            // Q signs: c0:-, c1:+, c2:+, c3:-   (b = q[c^1])
            const bool hiC = (quad & 2) != 0;
            float aE[8], bE[8], aO[8], bO[8];
#pragma unroll
            for (int j = 0; j < 8; ++j) {
                aE[j] = hiC ? sl1[j] : sl0[j];
                bE[j] = hiC ? sl0[j] : sl1[j];
                aO[j] = hiC ? sl3[j] : sl2[j];
                bO[j] = hiC ? sl2[j] : sl3[j];
            }
            F4U qc4, qs4;
            qc4.v = *(float4*)&qtrc[row][0];
            qs4.v = *(float4*)&qtrs[row][0];
            const float SC = 0.04508422017f;   // log2(e)/32
#pragma unroll
            for (int m = 0; m < 4; ++m) {
                float cm = qc4.f[m] * SC;
                float sm = qs4.f[m] * SC;
                float sE = hiC ? sm : -sm;     // c=1:+  c=0:-
                float vE[8], vO[8];
#pragma unroll
                for (int j = 0; j < 8; ++j) {
                    vE[j] = fmaf(bE[j], sE, aE[j] * cm);
                    vO[j] = fmaf(bO[j], -sE, aO[j] * cm);   // c=2:+  c=3:-
                }
                qa[set][2 * m]     = cvt8(vE);
                qa[set][2 * m + 1] = cvt8(vO);
            }
        }
        __syncthreads();   // qstage/qtr overlays now free
    }

    f32x4 Oacc[2][4] = {{{0,0,0,0},{0,0,0,0},{0,0,0,0},{0,0,0,0}},
                        {{0,0,0,0},{0,0,0,0},{0,0,0,0},{0,0,0,0}}};
    float mrow[2] = {-1e30f, -1e30f};   // per set: lane's Q-row = wv*32+set*16+nn
    float lrow[2] = {0.f, 0.f};

    // sigma-permuted QK row base: lane nn reads krot row (nn>>2)*8 + (nn&3)
    // (+ ks2*32 + hf*4), so D-slot (quad, r) holds key ks2*32+quad*8+hf*4+r.
    const int sigrow = ((nn >> 2) << 3) + (nn & 3);

    // ---- prologue: tile 0 into buf0, prefetch tile 1 ----
    BUILD(0, KROT_OFF, VTS_OFF);
    LOAD(64);
    __syncthreads();

    for (int ti = 0; ti < NTILES; ++ti) {
        _Float16 (*krot)[256] = reinterpret_cast<_Float16 (*)[256]>(
            smem + KROT_OFF + (ti & 1) * 32768);
        _Float16 (*vts)[64] = reinterpret_cast<_Float16 (*)[64]>(
            smem + VTS_OFF + (ti & 1) * 8192);

        // ---- QK^T swapped + sigma: sc[set][ks2][hf][r] =
        //      score(qrow = wv*32+set*16+nn, key = ks2*32+quad*8+hf*4+r) ----
        float sc[2][2][2][4];
        __builtin_amdgcn_s_setprio(1);
#pragma unroll
        for (int ks2 = 0; ks2 < 2; ++ks2)
#pragma unroll
            for (int hf = 0; hf < 2; ++hf) {
                const int keyb = ks2 * 32 + hf * 4 + sigrow;
                const int xr = hf * 4 + (nn & 3);      // keyb & 7
                f32x4 acc0 = {0, 0, 0, 0}, acc1 = {0, 0, 0, 0};
#pragma unroll
                for (int ks = 0; ks < 8; ++ks) {
                    f16x8 bK = *(const f16x8*)&krot[keyb][((ks * 4 + quad) ^ xr) * 8];
                    acc0 = __builtin_amdgcn_mfma_f32_16x16x32_f16(bK, qa[0][ks], acc0, 0, 0, 0);
                    acc1 = __builtin_amdgcn_mfma_f32_16x16x32_f16(bK, qa[1][ks], acc1, 0, 0, 0);
                }
#pragma unroll
                for (int r = 0; r < 4; ++r) {
                    sc[0][ks2][hf][r] = acc0[r];
                    sc[1][ks2][hf][r] = acc1[r];
                }
            }
        __builtin_amdgcn_s_setprio(0);

        // ---- build tile ti+1 into the other buffer (overlaps other waves' MFMA) ----
        if (ti + 1 < NTILES) {
            BUILD((ti + 1) * 64, KROT_OFF + ((ti + 1) & 1) * 32768,
                  VTS_OFF + ((ti + 1) & 1) * 8192);
            if (ti + 2 < NTILES) LOAD((ti + 2) * 64);
        }

        // ---- lane-local online softmax (base 2), defer-max THR=8;
        //      P packed in-register straight into PV A-frags ----
        f16x8 pf[2][2];
#pragma unroll
        for (int set = 0; set < 2; ++set) {
            float m0 = fmaxf(fmaxf(sc[set][0][0][0], sc[set][0][0][1]),
                             fmaxf(sc[set][0][0][2], sc[set][0][0][3]));
            float m1 = fmaxf(fmaxf(sc[set][0][1][0], sc[set][0][1][1]),
                             fmaxf(sc[set][0][1][2], sc[set][0][1][3]));
            float m2 = fmaxf(fmaxf(sc[set][1][0][0], sc[set][1][0][1]),
                             fmaxf(sc[set][1][0][2], sc[set][1][0][3]));
            float m3 = fmaxf(fmaxf(sc[set][1][1][0], sc[set][1][1][1]),
                             fmaxf(sc[set][1][1][2], sc[set][1][1][3]));
            float tm = fmaxf(fmaxf(m0, m1), fmaxf(m2, m3));
            tm = fmaxf(tm, __shfl_xor(tm, 16));
            tm = fmaxf(tm, __shfl_xor(tm, 32));   // all quads now hold row-max

            if (__any(tm > mrow[set] + 8.0f)) {   // wave-uniform rescale path
                float mnew  = fmaxf(mrow[set], tm);
                float alpha = __builtin_amdgcn_exp2f(mrow[set] - mnew);
                mrow[set] = mnew;
                lrow[set] *= alpha;
#pragma unroll
                for (int r = 0; r < 4; ++r) {
                    float ar = __shfl(alpha, quad * 4 + r, 64);
                    Oacc[set][0][r] *= ar; Oacc[set][1][r] *= ar;
                    Oacc[set][2][r] *= ar; Oacc[set][3][r] *= ar;
                }
            }

            float p[2][2][4];
#pragma unroll
            for (int ks2 = 0; ks2 < 2; ++ks2)
#pragma unroll
                for (int hf = 0; hf < 2; ++hf)
#pragma unroll
                    for (int r = 0; r < 4; ++r)
                        p[ks2][hf][r] =
                            __builtin_amdgcn_exp2f(sc[set][ks2][hf][r] - mrow[set]);

            float s0s = (p[0][0][0] + p[0][0][1]) + (p[0][0][2] + p[0][0][3]);
            float s1s = (p[0][1][0] + p[0][1][1]) + (p[0][1][2] + p[0][1][3]);
            float s2s = (p[1][0][0] + p[1][0][1]) + (p[1][0][2] + p[1][0][3]);
            float s3s = (p[1][1][0] + p[1][1][1]) + (p[1][1][2] + p[1][1][3]);
            float psum = (s0s + s1s) + (s2s + s3s);
            psum += __shfl_xor(psum, 16);
            psum += __shfl_xor(psum, 32);
            lrow[set] += psum;

            // pack: pf[set][ks2] elems j = hf*4+r  (keys quad*8+j of block ks2)
#pragma unroll
            for (int ks2 = 0; ks2 < 2; ++ks2) {
                H8U pk;
                pk.p[0] = __builtin_amdgcn_cvt_pkrtz(p[ks2][0][0], p[ks2][0][1]);
                pk.p[1] = __builtin_amdgcn_cvt_pkrtz(p[ks2][0][2], p[ks2][0][3]);
                pk.p[2] = __builtin_amdgcn_cvt_pkrtz(p[ks2][1][0], p[ks2][1][1]);
                pk.p[3] = __builtin_amdgcn_cvt_pkrtz(p[ks2][1][2], p[ks2][1][3]);
                pf[set][ks2] = pk.h;
            }
        }

        // ---- PV straight from registers (vf shared across sets) ----
        __builtin_amdgcn_s_setprio(1);
#pragma unroll
        for (int ks2 = 0; ks2 < 2; ++ks2)
#pragma unroll
            for (int et = 0; et < 4; ++et) {
                int e = et * 16 + nn;
                int se = ((nn & 7) ^ ((et * 2 + (nn >> 3)) & 7)) & 7;   // s(e)
                f16x8 vf = *(const f16x8*)&vts[e][((quad + 4 * ks2) ^ se) * 8];
                Oacc[0][et] = __builtin_amdgcn_mfma_f32_16x16x32_f16(pf[0][ks2], vf, Oacc[0][et], 0, 0, 0);
                Oacc[1][et] = __builtin_amdgcn_mfma_f32_16x16x32_f16(pf[1][ks2], vf, Oacc[1][et], 0, 0, 0);
            }
        __builtin_amdgcn_s_setprio(0);
        __syncthreads();   // build(ti+1) visible + all buf reads done
    }

    // ---- epilogue ----
    float* ob = out + ((size_t)((b * L_ + l0) * H_ + h)) * E_;
#pragma unroll
    for (int set = 0; set < 2; ++set)
#pragma unroll
        for (int r = 0; r < 4; ++r) {
            float lr = __shfl(lrow[set], quad * 4 + r, 64);
            float inv = 1.0f / lr;
            int row = wv * 32 + set * 16 + quad * 4 + r;   // 0..255
#pragma unroll
            for (int et = 0; et < 4; ++et)
                ob[(size_t)row * (H_ * E_) + et * 16 + nn] = Oacc[set][et][r] * inv;
        }
}

extern "C" void kernel_launch(void* const* d_in, const int* in_sizes, int n_in,
                              void* d_out, int out_size, void* d_ws, size_t ws_size,
                              hipStream_t stream) {
    const float* qp = (const float*)d_in[0];
    const float* kp = (const float*)d_in[1];
    const float* vp = (const float*)d_in[2];
    const float* qo = (const float*)d_in[3];
    const float* qt = (const float*)d_in[4];
    const float* ko = (const float*)d_in[5];
    const float* kt = (const float*)d_in[6];
    float* out = (float*)d_out;

    qattn9<<<dim3(B_ * H_ * (L_ / QBLK)), dim3(NTH), 0, stream>>>(
        qp, kp, vp, qo, qt, ko, kt, out);
}

// Round 9
// 187.089 us; speedup vs baseline: 1.1050x; 1.1050x over previous
//
#include <hip/hip_runtime.h>
#include <math.h>

// QuaternionAttention B=4, L=S=2048, H=8, E=64, M=4 (fp32 in/out).
// Round 17 = round 16 with the krot swizzle fixed. Round 16 (142.6us, WORSE
// than r15's 129.7) kept structure wins (in-register P via sigma-permuted QK,
// V^T double-XOR swizzle, pss deleted) but its QK read XOR xr=hf*4+(nn&3)
// only drew 2 lane bits -> 16 lanes on 4 bank groups = 4-way conflict on
// every QK b128 read (conflicts 1.61e7 -> 2.79e7, MfmaUtil 28.6 -> 25.9).
// Fix: per-key swizzle f(k) = (k&3) | ((k>>1)&4)  (bit2 of f = bit3 of k),
// applied at BUILD-write (swz) and QK-read (xr). For the sigma row
// keyb = ks2*32+(nn>>2)*8+hf*4+(nn&3): f(keyb) = nn&7 -- full 3-bit lane
// spread, 2-way (free), independent of hf/ks2. Write side stays conflict-free
// (swz per-key constant, 8 components span all 8 chunk groups).
// Everything else identical to round 16.

#define B_ 4
#define L_ 2048
#define S_ 2048
#define H_ 8
#define E_ 64
#define M_ 4
#define QBLK 256
#define NTH 512
#define NTILES 32

#define KROT_OFF 0          // 2 x 32KB
#define VTS_OFF  65536      // 2 x 8KB
#define QTRC_OFF 73728      // overlay vts buf1 (dead before BUILD(1))
#define QTRS_OFF 77824
#define SMEM_BYTES 81920

typedef _Float16 f16x4 __attribute__((ext_vector_type(4)));
typedef _Float16 f16x8 __attribute__((ext_vector_type(8)));
typedef __fp16 fp16x2 __attribute__((ext_vector_type(2)));   // cvt_pkrtz return type
typedef float f32x4 __attribute__((ext_vector_type(4)));

union H4U { f16x4 h; fp16x2 p[2]; };
union H8U { f16x8 h; fp16x2 p[4]; };
union F4U { float4 v; float f[4]; };

#if __has_builtin(__builtin_amdgcn_sinf) && __has_builtin(__builtin_amdgcn_cosf)
#define FSINCOS(ang, s, c) do { float _rv = (ang) * 0.15915494309189535f; \
    (s) = __builtin_amdgcn_sinf(_rv); (c) = __builtin_amdgcn_cosf(_rv); } while (0)
#else
#define FSINCOS(ang, s, c) __sincosf((ang), &(s), &(c))
#endif

__device__ __forceinline__ f16x4 cvt4(float x, float y, float z, float w) {
    H4U r;
    r.p[0] = __builtin_amdgcn_cvt_pkrtz(x, y);
    r.p[1] = __builtin_amdgcn_cvt_pkrtz(z, w);
    return r.h;
}
__device__ __forceinline__ f16x8 cvt8(const float* v) {
    H8U r;
#pragma unroll
    for (int i = 0; i < 4; ++i) r.p[i] = __builtin_amdgcn_cvt_pkrtz(v[2 * i], v[2 * i + 1]);
    return r.h;
}

__global__ __launch_bounds__(NTH)
void qattn10(const float* __restrict__ qp, const float* __restrict__ kp,
             const float* __restrict__ vp,
             const float* __restrict__ qo, const float* __restrict__ qt,
             const float* __restrict__ ko, const float* __restrict__ ktt,
             float* __restrict__ out)
{
    // XCD-chunked swizzle (256 blocks, bijective): each XCD gets 32
    // consecutive nl = 4 (b,h) groups.
    const int bid0 = blockIdx.x;                  // 0..255
    const int nl = (bid0 & 7) * 32 + (bid0 >> 3);
    const int l0 = (nl & 7) * QBLK;
    const int h  = (nl >> 3) & 7;
    const int b  = nl >> 6;
    const int t  = threadIdx.x;
    const int wv   = t >> 6;                      // 0..7
    const int lane = t & 63;
    const int quad = lane >> 4;
    const int nn   = lane & 15;

    __shared__ __align__(16) unsigned char smem[SMEM_BYTES];
    float (*qstage)[68] = reinterpret_cast<float (*)[68]>(smem);           // 69.6KB overlay
    float (*qtrc)[4] = reinterpret_cast<float (*)[4]>(smem + QTRC_OFF);
    float (*qtrs)[4] = reinterpret_cast<float (*)[4]>(smem + QTRS_OFF);

    const float* kb0 = kp  + ((size_t)((b * S_) * H_ + h)) * E_;
    const float* vb0 = vp  + ((size_t)((b * S_) * H_ + h)) * E_;
    const float* kob = ko  + ((size_t)((b * S_) * H_ + h)) * M_;
    const float* ktb = ktt + ((size_t)((b * S_) * H_ + h)) * M_;

    // K_rot build roles: 8 threads per key = 4 components x 2 e-halves
    const int key_r = t >> 3;       // 0..63
    const int ccr   = (t >> 1) & 3; // component
    const int eh    = t & 1;        // e-half within component
    const int swz   = (key_r & 3) | ((key_r >> 1) & 4);   // f(k): bit2 from k's bit3
    // V^T roles (upper 256 threads)
    const int tt = t & 255;
    const int kg = tt >> 4;         // key group (4 keys)
    const int eg = tt & 15;         // e group (4 e's)

    // ---- register pipeline: next tile's K slices, trig, V rows ----
    F4U kA[2], kB[2], omR, thR, vv[4];
    auto LOAD = [&](int s0) {
        const float* kr = kb0 + (size_t)(s0 + key_r) * (H_ * E_);
        kA[0].v = *(const float4*)(kr + ccr * 16 + eh * 8);            // a = k[cc]
        kA[1].v = *(const float4*)(kr + ccr * 16 + eh * 8 + 4);
        kB[0].v = *(const float4*)(kr + (ccr ^ 2) * 16 + eh * 8);      // b = k[cc^2]
        kB[1].v = *(const float4*)(kr + (ccr ^ 2) * 16 + eh * 8 + 4);
        omR.v = *(const float4*)(kob + (size_t)(s0 + key_r) * (H_ * M_));
        thR.v = *(const float4*)(ktb + (size_t)(s0 + key_r) * (H_ * M_));
        if (t >= 256) {
#pragma unroll
            for (int j = 0; j < 4; ++j)
                vv[j].v = *(const float4*)(vb0 + (size_t)(s0 + kg * 4 + j) * (H_ * E_) + eg * 4);
        }
    };

    // ---- build K_rot + V^T into the given LDS buffers from pipeline regs ----
    auto BUILD = [&](int s0, int koff, int voff) {
        _Float16 (*krw)[256] = reinterpret_cast<_Float16 (*)[256]>(smem + koff);
        _Float16 (*vtw)[64]  = reinterpret_cast<_Float16 (*)[64]>(smem + voff);
        {   // K signs: c0:-, c1:-, c2:+, c3:+
            float af[8], bf[8];
#pragma unroll
            for (int i2 = 0; i2 < 4; ++i2) {
                af[i2]     = kA[0].f[i2];
                af[4 + i2] = kA[1].f[i2];
                bf[i2]     = kB[0].f[i2];
                bf[4 + i2] = kB[1].f[i2];
            }
            float posk = (float)(s0 + key_r) * (1.0f / S_);
            float kcv[4], ksv[4];
#pragma unroll
            for (int m = 0; m < 4; ++m) {
                float ang = fmaf(omR.f[m], posk, thR.f[m]);
                FSINCOS(ang, ksv[m], kcv[m]);
            }
            const float sgn = (ccr >= 2) ? 1.f : -1.f;
#pragma unroll
            for (int m = 0; m < 4; ++m) {
                float cm = kcv[m], sm = ksv[m] * sgn;
                float vals[8];
#pragma unroll
                for (int i = 0; i < 8; ++i)
                    vals[i] = fmaf(bf[i], sm, af[i] * cm);
                int ch = (m * 8) | ((ccr * 2 + eh) ^ swz);
                *(f16x8*)&krw[key_r][ch * 8] = cvt8(vals);
            }
        }
        if (t >= 256) {   // V^T 4x4 register-block transpose, s(row) swizzle
#pragma unroll
            for (int e = 0; e < 4; ++e) {
                int row = eg * 4 + e;
                int srow = ((row & 7) ^ (row >> 3)) & 7;
                int ch = (kg >> 1) ^ srow;
                *(f16x4*)&vtw[row][ch * 8 + (kg & 1) * 4] =
                    cvt4(vv[0].f[e], vv[1].f[e], vv[2].f[e], vv[3].f[e]);
            }
        }
    };

    LOAD(0);   // tile-0 loads fly under Q_rot construction

    // ---- build Q_rot A-fragments once per block (scale log2(e)/32 folded) ----
    // Two sets per wave: set s covers rows wv*32 + s*16 + (0..15).
    f16x8 qa[2][8];
    {
        const float* qb = qp + ((size_t)((b * L_ + l0) * H_ + h)) * E_;
#pragma unroll
        for (int i = 0; i < 8; ++i) {
            int idx = t + NTH * i;                 // 0..4095
            int row = idx >> 4, c16 = idx & 15;
            *(float4*)&qstage[row][c16 * 4] =
                *(const float4*)(qb + (size_t)row * (H_ * E_) + c16 * 4);
        }
        {
            int row = t >> 1, m0 = (t & 1) * 2;    // 256 rows x 2 m-pairs
#pragma unroll
            for (int dm = 0; dm < 2; ++dm) {
                int m = m0 + dm;
                size_t off = (size_t)((b * L_ + l0 + row) * H_ + h) * M_ + m;
                float ang = qo[off] * ((float)(l0 + row) * (1.0f / L_)) + qt[off];
                float sv, cv;
                FSINCOS(ang, sv, cv);
                qtrc[row][m] = cv;
                qtrs[row][m] = sv;
            }
        }
        __syncthreads();
#pragma unroll
        for (int set = 0; set < 2; ++set) {
            const int row = wv * 32 + set * 16 + nn;   // A-frag row = lane&15
            const int i0 = (quad & 1) * 8;
            float sl0[8], sl1[8], sl2[8], sl3[8];
            *(float4*)&sl0[0] = *(float4*)&qstage[row][ 0 + i0];
            *(float4*)&sl0[4] = *(float4*)&qstage[row][ 4 + i0];
            *(float4*)&sl1[0] = *(float4*)&qstage[row][16 + i0];
            *(float4*)&sl1[4] = *(float4*)&qstage[row][20 + i0];
            *(float4*)&sl2[0] = *(float4*)&qstage[row][32 + i0];
            *(float4*)&sl2[4] = *(float4*)&qstage[row][36 + i0];
            *(float4*)&sl3[0] = *(float4*)&qstage[row][48 + i0];
            *(float4*)&sl3[4] = *(float4*)&qstage[row][52 + i0];
            // even ks -> c = quad>>1 (0 or 1); odd ks -> c+2.
            // Q signs: c0:-, c1:+, c2:+, c3:-   (b = q[c^1])
            const bool hiC = (quad & 2) != 0;
            float aE[8], bE[8], aO[8], bO[8];
#pragma unroll
            for (int j = 0; j < 8; ++j) {
                aE[j] = hiC ? sl1[j] : sl0[j];
                bE[j] = hiC ? sl0[j] : sl1[j];
                aO[j] = hiC ? sl3[j] : sl2[j];
                bO[j] = hiC ? sl2[j] : sl3[j];
            }
            F4U qc4, qs4;
            qc4.v = *(float4*)&qtrc[row][0];
            qs4.v = *(float4*)&qtrs[row][0];
            const float SC = 0.04508422017f;   // log2(e)/32
#pragma unroll
            for (int m = 0; m < 4; ++m) {
                float cm = qc4.f[m] * SC;
                float sm = qs4.f[m] * SC;
                float sE = hiC ? sm : -sm;     // c=1:+  c=0:-
                float vE[8], vO[8];
#pragma unroll
                for (int j = 0; j < 8; ++j) {
                    vE[j] = fmaf(bE[j], sE, aE[j] * cm);
                    vO[j] = fmaf(bO[j], -sE, aO[j] * cm);   // c=2:+  c=3:-
                }
                qa[set][2 * m]     = cvt8(vE);
                qa[set][2 * m + 1] = cvt8(vO);
            }
        }
        __syncthreads();   // qstage/qtr overlays now free
    }

    f32x4 Oacc[2][4] = {{{0,0,0,0},{0,0,0,0},{0,0,0,0},{0,0,0,0}},
                        {{0,0,0,0},{0,0,0,0},{0,0,0,0},{0,0,0,0}}};
    float mrow[2] = {-1e30f, -1e30f};   // per set: lane's Q-row = wv*32+set*16+nn
    float lrow[2] = {0.f, 0.f};

    // sigma-permuted QK row base: lane nn reads krot row (nn>>2)*8 + (nn&3)
    // (+ ks2*32 + hf*4), so D-slot (quad, r) holds key ks2*32+quad*8+hf*4+r.
    const int sigrow = ((nn >> 2) << 3) + (nn & 3);
    const int xr = nn & 7;   // = f(keyb) for every (ks2,hf): full 3-bit spread

    // ---- prologue: tile 0 into buf0, prefetch tile 1 ----
    BUILD(0, KROT_OFF, VTS_OFF);
    LOAD(64);
    __syncthreads();

    for (int ti = 0; ti < NTILES; ++ti) {
        _Float16 (*krot)[256] = reinterpret_cast<_Float16 (*)[256]>(
            smem + KROT_OFF + (ti & 1) * 32768);
        _Float16 (*vts)[64] = reinterpret_cast<_Float16 (*)[64]>(
            smem + VTS_OFF + (ti & 1) * 8192);

        // ---- QK^T swapped + sigma: sc[set][ks2][hf][r] =
        //      score(qrow = wv*32+set*16+nn, key = ks2*32+quad*8+hf*4+r) ----
        float sc[2][2][2][4];
        __builtin_amdgcn_s_setprio(1);
#pragma unroll
        for (int ks2 = 0; ks2 < 2; ++ks2)
#pragma unroll
            for (int hf = 0; hf < 2; ++hf) {
                const int keyb = ks2 * 32 + hf * 4 + sigrow;
                f32x4 acc0 = {0, 0, 0, 0}, acc1 = {0, 0, 0, 0};
#pragma unroll
                for (int ks = 0; ks < 8; ++ks) {
                    f16x8 bK = *(const f16x8*)&krot[keyb][((ks * 4 + quad) ^ xr) * 8];
                    acc0 = __builtin_amdgcn_mfma_f32_16x16x32_f16(bK, qa[0][ks], acc0, 0, 0, 0);
                    acc1 = __builtin_amdgcn_mfma_f32_16x16x32_f16(bK, qa[1][ks], acc1, 0, 0, 0);
                }
#pragma unroll
                for (int r = 0; r < 4; ++r) {
                    sc[0][ks2][hf][r] = acc0[r];
                    sc[1][ks2][hf][r] = acc1[r];
                }
            }
        __builtin_amdgcn_s_setprio(0);

        // ---- build tile ti+1 into the other buffer (overlaps other waves' MFMA) ----
        if (ti + 1 < NTILES) {
            BUILD((ti + 1) * 64, KROT_OFF + ((ti + 1) & 1) * 32768,
                  VTS_OFF + ((ti + 1) & 1) * 8192);
            if (ti + 2 < NTILES) LOAD((ti + 2) * 64);
        }

        // ---- lane-local online softmax (base 2), defer-max THR=8;
        //      P packed in-register straight into PV A-frags ----
        f16x8 pf[2][2];
#pragma unroll
        for (int set = 0; set < 2; ++set) {
            float m0 = fmaxf(fmaxf(sc[set][0][0][0], sc[set][0][0][1]),
                             fmaxf(sc[set][0][0][2], sc[set][0][0][3]));
            float m1 = fmaxf(fmaxf(sc[set][0][1][0], sc[set][0][1][1]),
                             fmaxf(sc[set][0][1][2], sc[set][0][1][3]));
            float m2 = fmaxf(fmaxf(sc[set][1][0][0], sc[set][1][0][1]),
                             fmaxf(sc[set][1][0][2], sc[set][1][0][3]));
            float m3 = fmaxf(fmaxf(sc[set][1][1][0], sc[set][1][1][1]),
                             fmaxf(sc[set][1][1][2], sc[set][1][1][3]));
            float tm = fmaxf(fmaxf(m0, m1), fmaxf(m2, m3));
            tm = fmaxf(tm, __shfl_xor(tm, 16));
            tm = fmaxf(tm, __shfl_xor(tm, 32));   // all quads now hold row-max

            if (__any(tm > mrow[set] + 8.0f)) {   // wave-uniform rescale path
                float mnew  = fmaxf(mrow[set], tm);
                float alpha = __builtin_amdgcn_exp2f(mrow[set] - mnew);
                mrow[set] = mnew;
                lrow[set] *= alpha;
#pragma unroll
                for (int r = 0; r < 4; ++r) {
                    float ar = __shfl(alpha, quad * 4 + r, 64);
                    Oacc[set][0][r] *= ar; Oacc[set][1][r] *= ar;
                    Oacc[set][2][r] *= ar; Oacc[set][3][r] *= ar;
                }
            }

            float p[2][2][4];
#pragma unroll
            for (int ks2 = 0; ks2 < 2; ++ks2)
#pragma unroll
                for (int hf = 0; hf < 2; ++hf)
#pragma unroll
                    for (int r = 0; r < 4; ++r)
                        p[ks2][hf][r] =
                            __builtin_amdgcn_exp2f(sc[set][ks2][hf][r] - mrow[set]);

            float s0s = (p[0][0][0] + p[0][0][1]) + (p[0][0][2] + p[0][0][3]);
            float s1s = (p[0][1][0] + p[0][1][1]) + (p[0][1][2] + p[0][1][3]);
            float s2s = (p[1][0][0] + p[1][0][1]) + (p[1][0][2] + p[1][0][3]);
            float s3s = (p[1][1][0] + p[1][1][1]) + (p[1][1][2] + p[1][1][3]);
            float psum = (s0s + s1s) + (s2s + s3s);
            psum += __shfl_xor(psum, 16);
            psum += __shfl_xor(psum, 32);
            lrow[set] += psum;

            // pack: pf[set][ks2] elems j = hf*4+r  (keys quad*8+j of block ks2)
#pragma unroll
            for (int ks2 = 0; ks2 < 2; ++ks2) {
                H8U pk;
                pk.p[0] = __builtin_amdgcn_cvt_pkrtz(p[ks2][0][0], p[ks2][0][1]);
                pk.p[1] = __builtin_amdgcn_cvt_pkrtz(p[ks2][0][2], p[ks2][0][3]);
                pk.p[2] = __builtin_amdgcn_cvt_pkrtz(p[ks2][1][0], p[ks2][1][1]);
                pk.p[3] = __builtin_amdgcn_cvt_pkrtz(p[ks2][1][2], p[ks2][1][3]);
                pf[set][ks2] = pk.h;
            }
        }

        // ---- PV straight from registers (vf shared across sets) ----
        __builtin_amdgcn_s_setprio(1);
#pragma unroll
        for (int ks2 = 0; ks2 < 2; ++ks2)
#pragma unroll
            for (int et = 0; et < 4; ++et) {
                int e = et * 16 + nn;
                int se = ((nn & 7) ^ ((et * 2 + (nn >> 3)) & 7)) & 7;   // s(e)
                f16x8 vf = *(const f16x8*)&vts[e][((quad + 4 * ks2) ^ se) * 8];
                Oacc[0][et] = __builtin_amdgcn_mfma_f32_16x16x32_f16(pf[0][ks2], vf, Oacc[0][et], 0, 0, 0);
                Oacc[1][et] = __builtin_amdgcn_mfma_f32_16x16x32_f16(pf[1][ks2], vf, Oacc[1][et], 0, 0, 0);
            }
        __builtin_amdgcn_s_setprio(0);
        __syncthreads();   // build(ti+1) visible + all buf reads done
    }

    // ---- epilogue ----
    float* ob = out + ((size_t)((b * L_ + l0) * H_ + h)) * E_;
#pragma unroll
    for (int set = 0; set < 2; ++set)
#pragma unroll
        for (int r = 0; r < 4; ++r) {
            float lr = __shfl(lrow[set], quad * 4 + r, 64);
            float inv = 1.0f / lr;
            int row = wv * 32 + set * 16 + quad * 4 + r;   // 0..255
#pragma unroll
            for (int et = 0; et < 4; ++et)
                ob[(size_t)row * (H_ * E_) + et * 16 + nn] = Oacc[set][et][r] * inv;
        }
}

extern "C" void kernel_launch(void* const* d_in, const int* in_sizes, int n_in,
                              void* d_out, int out_size, void* d_ws, size_t ws_size,
                              hipStream_t stream) {
    const float* qp = (const float*)d_in[0];
    const float* kp = (const float*)d_in[1];
    const float* vp = (const float*)d_in[2];
    const float* qo = (const float*)d_in[3];
    const float* qt = (const float*)d_in[4];
    const float* ko = (const float*)d_in[5];
    const float* kt = (const float*)d_in[6];
    float* out = (float*)d_out;

    qattn10<<<dim3(B_ * H_ * (L_ / QBLK)), dim3(NTH), 0, stream>>>(
        qp, kp, vp, qo, qt, ko, kt, out);
}